// Round 1
// baseline (629.752 us; speedup 1.0000x reference)
//
#include <hip/hip_runtime.h>
#include <hip/hip_bf16.h>

#define HDIM 1024
#define SEQ  2048
#define BATCH 32
#define M_TOTAL (BATCH * SEQ)   // 65536
#define BM 256
#define BN 256
#define BK 32
#define KSTEPS (HDIM / BK)      // 32
#define NSLICE 16               // 4 n-blocks x 4 n-waves

typedef __bf16 bf16x8 __attribute__((ext_vector_type(8)));
typedef float  f32x4  __attribute__((ext_vector_type(4)));
typedef unsigned short u16;
#define AS1 __attribute__((address_space(1)))
#define AS3 __attribute__((address_space(3)))

__device__ __forceinline__ u16 f2bf(float f) {
    unsigned int u = __float_as_uint(f);
    u += 0x7FFFu + ((u >> 16) & 1u);   // round-to-nearest-even
    return (u16)(u >> 16);
}

// ---- fp32 -> bf16, 8 elems/thread ----
__global__ __launch_bounds__(256) void cvt_kernel(const float* __restrict__ in,
                                                  u16* __restrict__ out) {
    size_t i = ((size_t)blockIdx.x * 256 + threadIdx.x) * 8;
    float4 f0 = *(const float4*)(in + i);
    float4 f1 = *(const float4*)(in + i + 4);
    uint4 v;
    v.x = (unsigned)f2bf(f0.x) | ((unsigned)f2bf(f0.y) << 16);
    v.y = (unsigned)f2bf(f0.z) | ((unsigned)f2bf(f0.w) << 16);
    v.z = (unsigned)f2bf(f1.x) | ((unsigned)f2bf(f1.y) << 16);
    v.w = (unsigned)f2bf(f1.z) | ((unsigned)f2bf(f1.w) << 16);
    *(uint4*)(out + i) = v;
}

// ---- qb[b][o] = query[b]·Wa_w[o] + Wa_b[o] + Ua_b[o] (fp32) ----
__global__ __launch_bounds__(256) void qb_kernel(const float* __restrict__ query,
                                                 const float* __restrict__ Wa_w,
                                                 const float* __restrict__ Wa_b,
                                                 const float* __restrict__ Ua_b,
                                                 float* __restrict__ qb) {
    __shared__ float qs[HDIM];
    const int b = blockIdx.x;
    const int tid = threadIdx.x;
    ((float4*)qs)[tid] = ((const float4*)(query + b * HDIM))[tid];
    __syncthreads();
    const int lane = tid & 63;
    const int w = tid >> 6;
    const int obase = blockIdx.y * 64 + w * 16;
    for (int i = 0; i < 16; i++) {
        int o = obase + i;
        const float4* wrow = (const float4*)(Wa_w + (size_t)o * HDIM);
        float s = 0.f;
        #pragma unroll
        for (int j = 0; j < 4; j++) {
            float4 wv = wrow[j * 64 + lane];
            float4 qv = ((const float4*)qs)[j * 64 + lane];
            s += wv.x * qv.x + wv.y * qv.y + wv.z * qv.z + wv.w * qv.w;
        }
        #pragma unroll
        for (int m = 1; m < 64; m <<= 1) s += __shfl_xor(s, m);
        if (lane == 0) qb[b * HDIM + o] = s + Wa_b[o] + Ua_b[o];
    }
}

// ---- GEMM keysb·Ua^T + fused tanh + Va dot -> deterministic score slices ----
// 256x256 tile, BK=32, 8 waves (2M x 4N), 4-slot LDS ring (128 KiB),
// counted vmcnt(8) pipeline (3 K-tiles in flight, never drain to 0 mid-loop),
// 2 phases x 16 MFMA per K-tile, XOR col-slot swizzle (stage src + ds_read),
// setprio around MFMA clusters, XCD-chunked block swizzle (nwg=1024 % 8 == 0).
__global__ __launch_bounds__(512, 2) void gemm_score_kernel(const u16* __restrict__ keysb,
                                                            const u16* __restrict__ uab,
                                                            const float* __restrict__ qb,
                                                            const float* __restrict__ vaw,
                                                            float* __restrict__ sp) {
    __shared__ __align__(16) u16 As[4][BM * BK];   // 4 x 16 KB
    __shared__ __align__(16) u16 Bs[4][BN * BK];   // 4 x 16 KB

    const int tid  = threadIdx.x;
    const int lane = tid & 63;
    const int w    = tid >> 6;          // 0..7
    const int wm   = w >> 2;            // 0..1  -> rows [wm*128, +128)
    const int wn   = w & 3;             // 0..3  -> cols [wn*64, +64)

    // XCD-chunked swizzle: 128 consecutive remapped blocks per XCD, n-fastest
    const int bid = blockIdx.y * 4 + blockIdx.x;         // dispatch order
    const int swz = (bid & 7) * 128 + (bid >> 3);        // bijective (1024 % 8 == 0)
    const int bx  = swz & 3;
    const int by  = swz >> 2;
    const int n0  = bx * BN;
    const int m0  = by * BM;

    // ---- staging addressing (linear LDS dest, pre-swizzled global source) ----
    // row = 64 B = 4 x 16B slots; LDS(r, s) holds global slot s ^ ((r>>1)&3)
    const int srow = lane >> 2;                          // row within 16-row chunk
    const int cs   = (lane & 3) ^ ((lane >> 3) & 3);     // swizzled source slot
    const u16* gA0 = keysb + (size_t)(m0 + w * 32 + srow) * HDIM + cs * 8;
    const u16* gB0 = uab   + (size_t)(n0 + w * 32 + srow) * HDIM + cs * 8;
    const int ldst = w * 32 * BK;                        // wave's 32-row group

    // ---- fragment read addressing (swizzled) ----
    const int fr = lane & 15;
    const int fq = lane >> 4;
    const int sA = fq ^ ((fr >> 1) & 3);                 // row-bit-independent
    const int aoff = (wm * 128 + fr) * BK + sA * 8;
    const int boff = (wn * 64  + fr) * BK + sA * 8;

    f32x4 acc[8][4] = {};

#define STAGE_A(kt) { \
    u16* d = &As[(kt) & 3][ldst]; \
    __builtin_amdgcn_global_load_lds((AS1 void*)(gA0 + (size_t)(kt) * BK), (AS3 void*)d, 16, 0, 0); \
    __builtin_amdgcn_global_load_lds((AS1 void*)(gA0 + (size_t)(kt) * BK + 16 * HDIM), (AS3 void*)(d + 16 * BK), 16, 0, 0); }
#define STAGE_B(kt) { \
    u16* d = &Bs[(kt) & 3][ldst]; \
    __builtin_amdgcn_global_load_lds((AS1 void*)(gB0 + (size_t)(kt) * BK), (AS3 void*)d, 16, 0, 0); \
    __builtin_amdgcn_global_load_lds((AS1 void*)(gB0 + (size_t)(kt) * BK + 16 * HDIM), (AS3 void*)(d + 16 * BK), 16, 0, 0); }

    // prologue: tiles 0,1,2 in flight (12 loads/wave)
    STAGE_A(0) STAGE_B(0)
    STAGE_A(1) STAGE_B(1)
    STAGE_A(2) STAGE_B(2)

    for (int t = 0; t < KSTEPS; ++t) {
        // tile t resident gate: outstanding = tiles {t+1, t+2} afterwards
        if (t < KSTEPS - 2)       asm volatile("s_waitcnt vmcnt(8)" ::: "memory");
        else if (t == KSTEPS - 2) asm volatile("s_waitcnt vmcnt(4)" ::: "memory");
        else                      asm volatile("s_waitcnt vmcnt(0)" ::: "memory");
        __builtin_amdgcn_s_barrier();   // all waves' tile-t loads landed

        const u16* ap = &As[t & 3][aoff];
        const u16* bp = &Bs[t & 3][boff];
        bf16x8 a[8], b[4];

        // ---- phase 0: quadrant mi 0-3 ----
        #pragma unroll
        for (int i = 0; i < 4; i++) a[i] = *(const bf16x8*)(ap + i * 16 * BK);
        #pragma unroll
        for (int i = 0; i < 4; i++) b[i] = *(const bf16x8*)(bp + i * 16 * BK);
        if (t + 3 < KSTEPS) STAGE_A(t + 3)       // writes slot (t-1)&3: reads done
        __builtin_amdgcn_s_barrier();
        asm volatile("s_waitcnt lgkmcnt(0)" ::: "memory");
        __builtin_amdgcn_sched_barrier(0);
        __builtin_amdgcn_s_setprio(1);
        #pragma unroll
        for (int mi = 0; mi < 4; mi++)
            #pragma unroll
            for (int ni = 0; ni < 4; ni++)
                acc[mi][ni] = __builtin_amdgcn_mfma_f32_16x16x32_bf16(a[mi], b[ni], acc[mi][ni], 0, 0, 0);
        __builtin_amdgcn_s_setprio(0);
        __builtin_amdgcn_s_barrier();

        // ---- phase 1: quadrant mi 4-7 (b[] stays in regs) ----
        #pragma unroll
        for (int i = 4; i < 8; i++) a[i] = *(const bf16x8*)(ap + i * 16 * BK);
        if (t + 3 < KSTEPS) STAGE_B(t + 3)
        __builtin_amdgcn_s_barrier();
        asm volatile("s_waitcnt lgkmcnt(0)" ::: "memory");
        __builtin_amdgcn_sched_barrier(0);
        __builtin_amdgcn_s_setprio(1);
        #pragma unroll
        for (int mi = 4; mi < 8; mi++)
            #pragma unroll
            for (int ni = 0; ni < 4; ni++)
                acc[mi][ni] = __builtin_amdgcn_mfma_f32_16x16x32_bf16(a[mi], b[ni], acc[mi][ni], 0, 0, 0);
        __builtin_amdgcn_s_setprio(0);
        // next iteration opens with vmcnt + barrier
    }
#undef STAGE_A
#undef STAGE_B

    // epilogue: h = tanh(acc + qb), partial score over this wave's 64 n-cols
    const int bidx = m0 >> 11;   // BM=256 divides SEQ=2048
    float qv[4], vv[4];
    #pragma unroll
    for (int ni = 0; ni < 4; ni++) {
        int n_g = n0 + wn * 64 + ni * 16 + fr;
        qv[ni] = qb[bidx * HDIM + n_g];
        vv[ni] = vaw[n_g];
    }
    const int slice = bx * 4 + wn;
    float* sl = sp + ((size_t)slice * BATCH + bidx) * SEQ;
    #pragma unroll
    for (int mi = 0; mi < 8; mi++) {
        #pragma unroll
        for (int r = 0; r < 4; r++) {
            float p = 0.f;
            #pragma unroll
            for (int ni = 0; ni < 4; ni++) {
                float x = acc[mi][ni][r] + qv[ni];
                float e = __expf(2.f * x);          // tanh = 1 - 2/(e^{2x}+1), NaN-free
                p += (1.f - 2.f / (e + 1.f)) * vv[ni];
            }
            p += __shfl_xor(p, 1);
            p += __shfl_xor(p, 2);
            p += __shfl_xor(p, 4);
            p += __shfl_xor(p, 8);
            if (fr == 0) {
                int s_g = (m0 + wm * 128 + mi * 16 + fq * 4 + r) & (SEQ - 1);
                sl[s_g] = p;
            }
        }
    }
}

// ---- softmax over SEQ per batch; sums 16 slices; zeroes ctx region ----
__global__ __launch_bounds__(256) void softmax_kernel(const float* __restrict__ sp,
                                                      float* __restrict__ weights,
                                                      float* __restrict__ ctx) {
    __shared__ float red[4];
    const int b = blockIdx.x;
    const int tid = threadIdx.x;
    float4 z = {0.f, 0.f, 0.f, 0.f};
    ((float4*)(ctx + b * HDIM))[tid] = z;       // zero context for atomics
    float v[8];
    float mx = -1e30f;
    #pragma unroll
    for (int i = 0; i < 8; i++) {
        int s = tid + i * 256;
        float a = 0.f;
        #pragma unroll
        for (int j = 0; j < NSLICE; j++) a += sp[((size_t)j * BATCH + b) * SEQ + s];
        v[i] = a;
        mx = fmaxf(mx, a);
    }
    #pragma unroll
    for (int m = 1; m < 64; m <<= 1) mx = fmaxf(mx, __shfl_xor(mx, m));
    if ((tid & 63) == 0) red[tid >> 6] = mx;
    __syncthreads();
    mx = fmaxf(fmaxf(red[0], red[1]), fmaxf(red[2], red[3]));
    float sum = 0.f;
    #pragma unroll
    for (int i = 0; i < 8; i++) { v[i] = __expf(v[i] - mx); sum += v[i]; }
    #pragma unroll
    for (int m = 1; m < 64; m <<= 1) sum += __shfl_xor(sum, m);
    __syncthreads();
    if ((tid & 63) == 0) red[tid >> 6] = sum;
    __syncthreads();
    sum = red[0] + red[1] + red[2] + red[3];
    float inv = 1.f / sum;
    #pragma unroll
    for (int i = 0; i < 8; i++) weights[b * SEQ + tid + i * 256] = v[i] * inv;
}

// ---- context[b][h] = sum_s w[b][s] * keysb[b][s][h] (bf16 keys) ----
__global__ __launch_bounds__(256) void context_kernel(const u16* __restrict__ keysb,
                                                      const float* __restrict__ weights,
                                                      float* __restrict__ ctx) {
    __shared__ float wsm[256];
    const int b = blockIdx.x;
    const int s0 = blockIdx.y * 256;
    const int tid = threadIdx.x;
    wsm[tid] = weights[b * SEQ + s0 + tid];
    __syncthreads();
    const int hq = tid & 127;
    const int sh = (tid >> 7) * 128;
    float a0 = 0.f, a1 = 0.f, a2 = 0.f, a3 = 0.f;
    float a4 = 0.f, a5 = 0.f, a6 = 0.f, a7 = 0.f;
    const uint4* kp = (const uint4*)(keysb + (size_t)b * SEQ * HDIM
                                     + (size_t)(s0 + sh) * HDIM) + hq;
    #pragma unroll 8
    for (int s = 0; s < 128; s++) {
        uint4 kv = kp[s * 128];            // row stride = 1024 u16 = 128 uint4
        float wv = wsm[sh + s];
        a0 += wv * __uint_as_float(kv.x << 16);
        a1 += wv * __uint_as_float(kv.x & 0xFFFF0000u);
        a2 += wv * __uint_as_float(kv.y << 16);
        a3 += wv * __uint_as_float(kv.y & 0xFFFF0000u);
        a4 += wv * __uint_as_float(kv.z << 16);
        a5 += wv * __uint_as_float(kv.z & 0xFFFF0000u);
        a6 += wv * __uint_as_float(kv.w << 16);
        a7 += wv * __uint_as_float(kv.w & 0xFFFF0000u);
    }
    float* o = ctx + b * HDIM + hq * 8;
    atomicAdd(o + 0, a0);
    atomicAdd(o + 1, a1);
    atomicAdd(o + 2, a2);
    atomicAdd(o + 3, a3);
    atomicAdd(o + 4, a4);
    atomicAdd(o + 5, a5);
    atomicAdd(o + 6, a6);
    atomicAdd(o + 7, a7);
}

extern "C" void kernel_launch(void* const* d_in, const int* in_sizes, int n_in,
                              void* d_out, int out_size, void* d_ws, size_t ws_size,
                              hipStream_t stream) {
    const float* query = (const float*)d_in[0];
    const float* keys  = (const float*)d_in[1];
    const float* Wa_w  = (const float*)d_in[2];
    const float* Wa_b  = (const float*)d_in[3];
    const float* Ua_w  = (const float*)d_in[4];
    const float* Ua_b  = (const float*)d_in[5];
    const float* Va_w  = (const float*)d_in[6];
    // Va_b unused: softmax is shift-invariant.
    float* out = (float*)d_out;   // [0, 32768) context, [32768, 98304) weights

    char* ws = (char*)d_ws;
    u16*  keysb = (u16*)ws;                                     // 134217728 B
    u16*  uab   = (u16*)(ws + 134217728);                       //   2097152 B
    float* qb   = (float*)(ws + 134217728 + 2097152);           //    131072 B
    float* sp   = (float*)(ws + 134217728 + 2097152 + 131072);  //   4194304 B (16 slices)

    cvt_kernel<<<(BATCH * SEQ * HDIM) / 2048, 256, 0, stream>>>(keys, keysb);
    cvt_kernel<<<(HDIM * HDIM) / 2048, 256, 0, stream>>>(Ua_w, uab);
    qb_kernel<<<dim3(BATCH, HDIM / 64), 256, 0, stream>>>(query, Wa_w, Wa_b, Ua_b, qb);
    gemm_score_kernel<<<dim3(HDIM / BN, M_TOTAL / BM), 512, 0, stream>>>(keysb, uab, qb, Va_w, sp);
    softmax_kernel<<<BATCH, 256, 0, stream>>>(sp, out + BATCH * HDIM, out);
    context_kernel<<<dim3(BATCH, 8), 256, 0, stream>>>(keysb, out + BATCH * HDIM, out);
}

// Round 2
// 614.600 us; speedup vs baseline: 1.0247x; 1.0247x over previous
//
#include <hip/hip_runtime.h>
#include <hip/hip_bf16.h>

#define HDIM 1024
#define SEQ  2048
#define BATCH 32
#define M_TOTAL (BATCH * SEQ)   // 65536
#define BM 256
#define BN 256
#define BK 32
#define KSTEPS (HDIM / BK)      // 32
#define NSLICE 16               // 4 n-blocks x 4 n-waves

typedef __bf16 bf16x8 __attribute__((ext_vector_type(8)));
typedef float  f32x4  __attribute__((ext_vector_type(4)));
typedef unsigned short u16;
#define AS1 __attribute__((address_space(1)))
#define AS3 __attribute__((address_space(3)))

__device__ __forceinline__ u16 f2bf(float f) {
    unsigned int u = __float_as_uint(f);
    u += 0x7FFFu + ((u >> 16) & 1u);   // round-to-nearest-even
    return (u16)(u >> 16);
}

// ---- fp32 -> bf16, 8 elems/thread ----
__global__ __launch_bounds__(256) void cvt_kernel(const float* __restrict__ in,
                                                  u16* __restrict__ out) {
    size_t i = ((size_t)blockIdx.x * 256 + threadIdx.x) * 8;
    float4 f0 = *(const float4*)(in + i);
    float4 f1 = *(const float4*)(in + i + 4);
    uint4 v;
    v.x = (unsigned)f2bf(f0.x) | ((unsigned)f2bf(f0.y) << 16);
    v.y = (unsigned)f2bf(f0.z) | ((unsigned)f2bf(f0.w) << 16);
    v.z = (unsigned)f2bf(f1.x) | ((unsigned)f2bf(f1.y) << 16);
    v.w = (unsigned)f2bf(f1.z) | ((unsigned)f2bf(f1.w) << 16);
    *(uint4*)(out + i) = v;
}

// ---- qb[b][o] = query[b]·Wa_w[o] + Wa_b[o] + Ua_b[o] (fp32) ----
__global__ __launch_bounds__(256) void qb_kernel(const float* __restrict__ query,
                                                 const float* __restrict__ Wa_w,
                                                 const float* __restrict__ Wa_b,
                                                 const float* __restrict__ Ua_b,
                                                 float* __restrict__ qb) {
    __shared__ float qs[HDIM];
    const int b = blockIdx.x;
    const int tid = threadIdx.x;
    ((float4*)qs)[tid] = ((const float4*)(query + b * HDIM))[tid];
    __syncthreads();
    const int lane = tid & 63;
    const int w = tid >> 6;
    const int obase = blockIdx.y * 64 + w * 16;
    for (int i = 0; i < 16; i++) {
        int o = obase + i;
        const float4* wrow = (const float4*)(Wa_w + (size_t)o * HDIM);
        float s = 0.f;
        #pragma unroll
        for (int j = 0; j < 4; j++) {
            float4 wv = wrow[j * 64 + lane];
            float4 qv = ((const float4*)qs)[j * 64 + lane];
            s += wv.x * qv.x + wv.y * qv.y + wv.z * qv.z + wv.w * qv.w;
        }
        #pragma unroll
        for (int m = 1; m < 64; m <<= 1) s += __shfl_xor(s, m);
        if (lane == 0) qb[b * HDIM + o] = s + Wa_b[o] + Ua_b[o];
    }
}

// raw ds_read_b128: invisible to SIInsertWaitcnts' LDS-DMA alias logic, so the
// counted-vmcnt ring is not silently demoted to drain-per-phase. All lgkm
// waits are manual (rule #18: lgkmcnt(0) + sched_barrier(0) before MFMA).
#define DSREAD(dst, base, imm) \
    asm volatile("ds_read_b128 %0, %1 offset:" #imm : "=v"(dst) : "v"(base))

// ---- GEMM keysb·Ua^T + fused tanh + Va dot -> deterministic score slices ----
// 256x256 tile, BK=32, 8 waves (2M x 4N), 4-slot LDS ring (128 KiB),
// counted vmcnt(8) pipeline (3 K-tiles in flight, never drain to 0 mid-loop),
// asm ds_read fragments, setprio around MFMA clusters, XCD-chunked swizzle.
__global__ __launch_bounds__(512, 2) void gemm_score_kernel(const u16* __restrict__ keysb,
                                                            const u16* __restrict__ uab,
                                                            const float* __restrict__ qb,
                                                            const float* __restrict__ vaw,
                                                            float* __restrict__ sp) {
    __shared__ __align__(16) u16 As[4][BM * BK];   // 4 x 16 KB
    __shared__ __align__(16) u16 Bs[4][BN * BK];   // 4 x 16 KB

    const int tid  = threadIdx.x;
    const int lane = tid & 63;
    const int w    = tid >> 6;          // 0..7
    const int wm   = w >> 2;            // 0..1  -> rows [wm*128, +128)
    const int wn   = w & 3;             // 0..3  -> cols [wn*64, +64)

    // XCD-chunked swizzle: 128 consecutive remapped blocks per XCD, n-fastest
    const int bid = blockIdx.y * 4 + blockIdx.x;         // dispatch order
    const int swz = (bid & 7) * 128 + (bid >> 3);        // bijective (1024 % 8 == 0)
    const int bx  = swz & 3;
    const int by  = swz >> 2;
    const int n0  = bx * BN;
    const int m0  = by * BM;

    // ---- staging addressing (linear LDS dest, pre-swizzled global source) ----
    // row = 64 B = 4 x 16B slots; LDS(r, s) holds global slot s ^ ((r>>1)&3)
    const int srow = lane >> 2;                          // row within 16-row chunk
    const int cs   = (lane & 3) ^ ((lane >> 3) & 3);     // swizzled source slot
    const u16* gA0 = keysb + (size_t)(m0 + w * 32 + srow) * HDIM + cs * 8;
    const u16* gB0 = uab   + (size_t)(n0 + w * 32 + srow) * HDIM + cs * 8;
    const int ldst = w * 32 * BK;                        // wave's 32-row group

    // ---- fragment read addressing (swizzled), as LDS byte offsets ----
    const int fr = lane & 15;
    const int fq = lane >> 4;
    const int sA = fq ^ ((fr >> 1) & 3);                 // row-bit-independent
    const unsigned aB0 = (unsigned)(unsigned long long)(const AS3 u16*)&As[0][0]
                       + (unsigned)(((wm * 128 + fr) * BK + sA * 8) * 2);
    const unsigned bB0 = (unsigned)(unsigned long long)(const AS3 u16*)&Bs[0][0]
                       + (unsigned)(((wn * 64  + fr) * BK + sA * 8) * 2);

    f32x4 acc[8][4] = {};

#define STAGE_A(kt) { \
    u16* d = &As[(kt) & 3][ldst]; \
    __builtin_amdgcn_global_load_lds((AS1 void*)(gA0 + (size_t)(kt) * BK), (AS3 void*)d, 16, 0, 0); \
    __builtin_amdgcn_global_load_lds((AS1 void*)(gA0 + (size_t)(kt) * BK + 16 * HDIM), (AS3 void*)(d + 16 * BK), 16, 0, 0); }
#define STAGE_B(kt) { \
    u16* d = &Bs[(kt) & 3][ldst]; \
    __builtin_amdgcn_global_load_lds((AS1 void*)(gB0 + (size_t)(kt) * BK), (AS3 void*)d, 16, 0, 0); \
    __builtin_amdgcn_global_load_lds((AS1 void*)(gB0 + (size_t)(kt) * BK + 16 * HDIM), (AS3 void*)(d + 16 * BK), 16, 0, 0); }

    // prologue: tiles 0,1,2 in flight (12 loads/wave)
    STAGE_A(0) STAGE_B(0)
    STAGE_A(1) STAGE_B(1)
    STAGE_A(2) STAGE_B(2)

    for (int t = 0; t < KSTEPS; ++t) {
        // tile t resident gate: outstanding afterwards = tiles {t+1, t+2}
        if (t < KSTEPS - 2)       asm volatile("s_waitcnt vmcnt(8)" ::: "memory");
        else if (t == KSTEPS - 2) asm volatile("s_waitcnt vmcnt(4)" ::: "memory");
        else                      asm volatile("s_waitcnt vmcnt(0)" ::: "memory");
        __builtin_amdgcn_s_barrier();   // all waves' tile-t loads landed

        const unsigned at = aB0 + ((t & 3) << 14);   // slot stride 16 KiB
        const unsigned bt = bB0 + ((t & 3) << 14);
        bf16x8 a0, a1, a2, a3, a4, a5, a6, a7, b0, b1, b2, b3;

        // ---- phase 0: quadrant mi 0-3 ----
        DSREAD(a0, at, 0);    DSREAD(a1, at, 1024);
        DSREAD(a2, at, 2048); DSREAD(a3, at, 3072);
        DSREAD(b0, bt, 0);    DSREAD(b1, bt, 1024);
        DSREAD(b2, bt, 2048); DSREAD(b3, bt, 3072);
        if (t + 3 < KSTEPS) STAGE_A(t + 3)       // writes slot (t-1)&3: reads done
        __builtin_amdgcn_s_barrier();
        asm volatile("s_waitcnt lgkmcnt(0)" ::: "memory");
        __builtin_amdgcn_sched_barrier(0);
        __builtin_amdgcn_s_setprio(1);
        acc[0][0] = __builtin_amdgcn_mfma_f32_16x16x32_bf16(a0, b0, acc[0][0], 0, 0, 0);
        acc[0][1] = __builtin_amdgcn_mfma_f32_16x16x32_bf16(a0, b1, acc[0][1], 0, 0, 0);
        acc[0][2] = __builtin_amdgcn_mfma_f32_16x16x32_bf16(a0, b2, acc[0][2], 0, 0, 0);
        acc[0][3] = __builtin_amdgcn_mfma_f32_16x16x32_bf16(a0, b3, acc[0][3], 0, 0, 0);
        acc[1][0] = __builtin_amdgcn_mfma_f32_16x16x32_bf16(a1, b0, acc[1][0], 0, 0, 0);
        acc[1][1] = __builtin_amdgcn_mfma_f32_16x16x32_bf16(a1, b1, acc[1][1], 0, 0, 0);
        acc[1][2] = __builtin_amdgcn_mfma_f32_16x16x32_bf16(a1, b2, acc[1][2], 0, 0, 0);
        acc[1][3] = __builtin_amdgcn_mfma_f32_16x16x32_bf16(a1, b3, acc[1][3], 0, 0, 0);
        acc[2][0] = __builtin_amdgcn_mfma_f32_16x16x32_bf16(a2, b0, acc[2][0], 0, 0, 0);
        acc[2][1] = __builtin_amdgcn_mfma_f32_16x16x32_bf16(a2, b1, acc[2][1], 0, 0, 0);
        acc[2][2] = __builtin_amdgcn_mfma_f32_16x16x32_bf16(a2, b2, acc[2][2], 0, 0, 0);
        acc[2][3] = __builtin_amdgcn_mfma_f32_16x16x32_bf16(a2, b3, acc[2][3], 0, 0, 0);
        acc[3][0] = __builtin_amdgcn_mfma_f32_16x16x32_bf16(a3, b0, acc[3][0], 0, 0, 0);
        acc[3][1] = __builtin_amdgcn_mfma_f32_16x16x32_bf16(a3, b1, acc[3][1], 0, 0, 0);
        acc[3][2] = __builtin_amdgcn_mfma_f32_16x16x32_bf16(a3, b2, acc[3][2], 0, 0, 0);
        acc[3][3] = __builtin_amdgcn_mfma_f32_16x16x32_bf16(a3, b3, acc[3][3], 0, 0, 0);
        __builtin_amdgcn_s_setprio(0);
        __builtin_amdgcn_s_barrier();

        // ---- phase 1: quadrant mi 4-7 (b0-b3 stay in regs) ----
        DSREAD(a4, at, 4096); DSREAD(a5, at, 5120);
        DSREAD(a6, at, 6144); DSREAD(a7, at, 7168);
        if (t + 3 < KSTEPS) STAGE_B(t + 3)
        __builtin_amdgcn_s_barrier();
        asm volatile("s_waitcnt lgkmcnt(0)" ::: "memory");
        __builtin_amdgcn_sched_barrier(0);
        __builtin_amdgcn_s_setprio(1);
        acc[4][0] = __builtin_amdgcn_mfma_f32_16x16x32_bf16(a4, b0, acc[4][0], 0, 0, 0);
        acc[4][1] = __builtin_amdgcn_mfma_f32_16x16x32_bf16(a4, b1, acc[4][1], 0, 0, 0);
        acc[4][2] = __builtin_amdgcn_mfma_f32_16x16x32_bf16(a4, b2, acc[4][2], 0, 0, 0);
        acc[4][3] = __builtin_amdgcn_mfma_f32_16x16x32_bf16(a4, b3, acc[4][3], 0, 0, 0);
        acc[5][0] = __builtin_amdgcn_mfma_f32_16x16x32_bf16(a5, b0, acc[5][0], 0, 0, 0);
        acc[5][1] = __builtin_amdgcn_mfma_f32_16x16x32_bf16(a5, b1, acc[5][1], 0, 0, 0);
        acc[5][2] = __builtin_amdgcn_mfma_f32_16x16x32_bf16(a5, b2, acc[5][2], 0, 0, 0);
        acc[5][3] = __builtin_amdgcn_mfma_f32_16x16x32_bf16(a5, b3, acc[5][3], 0, 0, 0);
        acc[6][0] = __builtin_amdgcn_mfma_f32_16x16x32_bf16(a6, b0, acc[6][0], 0, 0, 0);
        acc[6][1] = __builtin_amdgcn_mfma_f32_16x16x32_bf16(a6, b1, acc[6][1], 0, 0, 0);
        acc[6][2] = __builtin_amdgcn_mfma_f32_16x16x32_bf16(a6, b2, acc[6][2], 0, 0, 0);
        acc[6][3] = __builtin_amdgcn_mfma_f32_16x16x32_bf16(a6, b3, acc[6][3], 0, 0, 0);
        acc[7][0] = __builtin_amdgcn_mfma_f32_16x16x32_bf16(a7, b0, acc[7][0], 0, 0, 0);
        acc[7][1] = __builtin_amdgcn_mfma_f32_16x16x32_bf16(a7, b1, acc[7][1], 0, 0, 0);
        acc[7][2] = __builtin_amdgcn_mfma_f32_16x16x32_bf16(a7, b2, acc[7][2], 0, 0, 0);
        acc[7][3] = __builtin_amdgcn_mfma_f32_16x16x32_bf16(a7, b3, acc[7][3], 0, 0, 0);
        __builtin_amdgcn_s_setprio(0);
        // next iteration opens with vmcnt gate + barrier
    }
#undef STAGE_A
#undef STAGE_B

    // epilogue: h = tanh(acc + qb), partial score over this wave's 64 n-cols
    const int bidx = m0 >> 11;   // BM=256 divides SEQ=2048
    float qv[4], vv[4];
    #pragma unroll
    for (int ni = 0; ni < 4; ni++) {
        int n_g = n0 + wn * 64 + ni * 16 + fr;
        qv[ni] = qb[bidx * HDIM + n_g];
        vv[ni] = vaw[n_g];
    }
    const int slice = bx * 4 + wn;
    float* sl = sp + ((size_t)slice * BATCH + bidx) * SEQ;
    #pragma unroll
    for (int mi = 0; mi < 8; mi++) {
        #pragma unroll
        for (int r = 0; r < 4; r++) {
            float p = 0.f;
            #pragma unroll
            for (int ni = 0; ni < 4; ni++) {
                float x = acc[mi][ni][r] + qv[ni];
                float e = __expf(2.f * x);          // tanh = 1 - 2/(e^{2x}+1), NaN-free
                p += (1.f - 2.f / (e + 1.f)) * vv[ni];
            }
            p += __shfl_xor(p, 1);
            p += __shfl_xor(p, 2);
            p += __shfl_xor(p, 4);
            p += __shfl_xor(p, 8);
            if (fr == 0) {
                int s_g = (m0 + wm * 128 + mi * 16 + fq * 4 + r) & (SEQ - 1);
                sl[s_g] = p;
            }
        }
    }
}

// ---- softmax over SEQ per batch; sums 16 slices; zeroes ctx region ----
__global__ __launch_bounds__(256) void softmax_kernel(const float* __restrict__ sp,
                                                      float* __restrict__ weights,
                                                      float* __restrict__ ctx) {
    __shared__ float red[4];
    const int b = blockIdx.x;
    const int tid = threadIdx.x;
    float4 z = {0.f, 0.f, 0.f, 0.f};
    ((float4*)(ctx + b * HDIM))[tid] = z;       // zero context for atomics
    float v[8];
    float mx = -1e30f;
    #pragma unroll
    for (int i = 0; i < 8; i++) {
        int s = tid + i * 256;
        float a = 0.f;
        #pragma unroll
        for (int j = 0; j < NSLICE; j++) a += sp[((size_t)j * BATCH + b) * SEQ + s];
        v[i] = a;
        mx = fmaxf(mx, a);
    }
    #pragma unroll
    for (int m = 1; m < 64; m <<= 1) mx = fmaxf(mx, __shfl_xor(mx, m));
    if ((tid & 63) == 0) red[tid >> 6] = mx;
    __syncthreads();
    mx = fmaxf(fmaxf(red[0], red[1]), fmaxf(red[2], red[3]));
    float sum = 0.f;
    #pragma unroll
    for (int i = 0; i < 8; i++) { v[i] = __expf(v[i] - mx); sum += v[i]; }
    #pragma unroll
    for (int m = 1; m < 64; m <<= 1) sum += __shfl_xor(sum, m);
    __syncthreads();
    if ((tid & 63) == 0) red[tid >> 6] = sum;
    __syncthreads();
    sum = red[0] + red[1] + red[2] + red[3];
    float inv = 1.f / sum;
    #pragma unroll
    for (int i = 0; i < 8; i++) weights[b * SEQ + tid + i * 256] = v[i] * inv;
}

// ---- context[b][h] = sum_s w[b][s] * keysb[b][s][h] (bf16 keys) ----
__global__ __launch_bounds__(256) void context_kernel(const u16* __restrict__ keysb,
                                                      const float* __restrict__ weights,
                                                      float* __restrict__ ctx) {
    __shared__ float wsm[256];
    const int b = blockIdx.x;
    const int s0 = blockIdx.y * 256;
    const int tid = threadIdx.x;
    wsm[tid] = weights[b * SEQ + s0 + tid];
    __syncthreads();
    const int hq = tid & 127;
    const int sh = (tid >> 7) * 128;
    float a0 = 0.f, a1 = 0.f, a2 = 0.f, a3 = 0.f;
    float a4 = 0.f, a5 = 0.f, a6 = 0.f, a7 = 0.f;
    const uint4* kp = (const uint4*)(keysb + (size_t)b * SEQ * HDIM
                                     + (size_t)(s0 + sh) * HDIM) + hq;
    #pragma unroll 8
    for (int s = 0; s < 128; s++) {
        uint4 kv = kp[s * 128];            // row stride = 1024 u16 = 128 uint4
        float wv = wsm[sh + s];
        a0 += wv * __uint_as_float(kv.x << 16);
        a1 += wv * __uint_as_float(kv.x & 0xFFFF0000u);
        a2 += wv * __uint_as_float(kv.y << 16);
        a3 += wv * __uint_as_float(kv.y & 0xFFFF0000u);
        a4 += wv * __uint_as_float(kv.z << 16);
        a5 += wv * __uint_as_float(kv.z & 0xFFFF0000u);
        a6 += wv * __uint_as_float(kv.w << 16);
        a7 += wv * __uint_as_float(kv.w & 0xFFFF0000u);
    }
    float* o = ctx + b * HDIM + hq * 8;
    atomicAdd(o + 0, a0);
    atomicAdd(o + 1, a1);
    atomicAdd(o + 2, a2);
    atomicAdd(o + 3, a3);
    atomicAdd(o + 4, a4);
    atomicAdd(o + 5, a5);
    atomicAdd(o + 6, a6);
    atomicAdd(o + 7, a7);
}

extern "C" void kernel_launch(void* const* d_in, const int* in_sizes, int n_in,
                              void* d_out, int out_size, void* d_ws, size_t ws_size,
                              hipStream_t stream) {
    const float* query = (const float*)d_in[0];
    const float* keys  = (const float*)d_in[1];
    const float* Wa_w  = (const float*)d_in[2];
    const float* Wa_b  = (const float*)d_in[3];
    const float* Ua_w  = (const float*)d_in[4];
    const float* Ua_b  = (const float*)d_in[5];
    const float* Va_w  = (const float*)d_in[6];
    // Va_b unused: softmax is shift-invariant.
    float* out = (float*)d_out;   // [0, 32768) context, [32768, 98304) weights

    char* ws = (char*)d_ws;
    u16*  keysb = (u16*)ws;                                     // 134217728 B
    u16*  uab   = (u16*)(ws + 134217728);                       //   2097152 B
    float* qb   = (float*)(ws + 134217728 + 2097152);           //    131072 B
    float* sp   = (float*)(ws + 134217728 + 2097152 + 131072);  //   4194304 B (16 slices)

    cvt_kernel<<<(BATCH * SEQ * HDIM) / 2048, 256, 0, stream>>>(keys, keysb);
    cvt_kernel<<<(HDIM * HDIM) / 2048, 256, 0, stream>>>(Ua_w, uab);
    qb_kernel<<<dim3(BATCH, HDIM / 64), 256, 0, stream>>>(query, Wa_w, Wa_b, Ua_b, qb);
    gemm_score_kernel<<<dim3(HDIM / BN, M_TOTAL / BM), 512, 0, stream>>>(keysb, uab, qb, Va_w, sp);
    softmax_kernel<<<BATCH, 256, 0, stream>>>(sp, out + BATCH * HDIM, out);
    context_kernel<<<dim3(BATCH, 8), 256, 0, stream>>>(keysb, out + BATCH * HDIM, out);
}

// Round 4
// 598.588 us; speedup vs baseline: 1.0521x; 1.0267x over previous
//
#include <hip/hip_runtime.h>
#include <hip/hip_bf16.h>

#define HDIM 1024
#define SEQ  2048
#define BATCH 32
#define M_TOTAL (BATCH * SEQ)   // 65536
#define BM 256
#define BN 256
#define BK 32
#define KSTEPS (HDIM / BK)      // 32
#define NSLICE 16               // 4 n-blocks x 4 n-waves

typedef __bf16 bf16x8 __attribute__((ext_vector_type(8)));
typedef float  f32x4  __attribute__((ext_vector_type(4)));
typedef unsigned short u16;
#define AS1 __attribute__((address_space(1)))
#define AS3 __attribute__((address_space(3)))

__device__ __forceinline__ u16 f2bf(float f) {
    unsigned int u = __float_as_uint(f);
    u += 0x7FFFu + ((u >> 16) & 1u);   // round-to-nearest-even
    return (u16)(u >> 16);
}

// ---- fp32 -> bf16, 8 elems/thread ----
__global__ __launch_bounds__(256) void cvt_kernel(const float* __restrict__ in,
                                                  u16* __restrict__ out) {
    size_t i = ((size_t)blockIdx.x * 256 + threadIdx.x) * 8;
    float4 f0 = *(const float4*)(in + i);
    float4 f1 = *(const float4*)(in + i + 4);
    uint4 v;
    v.x = (unsigned)f2bf(f0.x) | ((unsigned)f2bf(f0.y) << 16);
    v.y = (unsigned)f2bf(f0.z) | ((unsigned)f2bf(f0.w) << 16);
    v.z = (unsigned)f2bf(f1.x) | ((unsigned)f2bf(f1.y) << 16);
    v.w = (unsigned)f2bf(f1.z) | ((unsigned)f2bf(f1.w) << 16);
    *(uint4*)(out + i) = v;
}

// ---- qb[b][o] = query[b]·Wa_w[o] + Wa_b[o] + Ua_b[o] (fp32) ----
__global__ __launch_bounds__(256) void qb_kernel(const float* __restrict__ query,
                                                 const float* __restrict__ Wa_w,
                                                 const float* __restrict__ Wa_b,
                                                 const float* __restrict__ Ua_b,
                                                 float* __restrict__ qb) {
    __shared__ float qs[HDIM];
    const int b = blockIdx.x;
    const int tid = threadIdx.x;
    ((float4*)qs)[tid] = ((const float4*)(query + b * HDIM))[tid];
    __syncthreads();
    const int lane = tid & 63;
    const int w = tid >> 6;
    const int obase = blockIdx.y * 64 + w * 16;
    for (int i = 0; i < 16; i++) {
        int o = obase + i;
        const float4* wrow = (const float4*)(Wa_w + (size_t)o * HDIM);
        float s = 0.f;
        #pragma unroll
        for (int j = 0; j < 4; j++) {
            float4 wv = wrow[j * 64 + lane];
            float4 qv = ((const float4*)qs)[j * 64 + lane];
            s += wv.x * qv.x + wv.y * qv.y + wv.z * qv.z + wv.w * qv.w;
        }
        #pragma unroll
        for (int m = 1; m < 64; m <<= 1) s += __shfl_xor(s, m);
        if (lane == 0) qb[b * HDIM + o] = s + Wa_b[o] + Ua_b[o];
    }
}

// raw ds_read_b128 (invisible to LDS-DMA alias waitcnt logic); all lgkm waits
// are manual COUNTED waits (rule #18: wait + sched_barrier(0) before MFMA).
#define DSREAD(dst, base, imm) \
    asm volatile("ds_read_b128 %0, %1 offset:" #imm : "=v"(dst) : "v"(base))

#define MFMA4(mi, av, b0v, b1v, b2v, b3v) \
    acc[mi][0] = __builtin_amdgcn_mfma_f32_16x16x32_bf16(av, b0v, acc[mi][0], 0, 0, 0); \
    acc[mi][1] = __builtin_amdgcn_mfma_f32_16x16x32_bf16(av, b1v, acc[mi][1], 0, 0, 0); \
    acc[mi][2] = __builtin_amdgcn_mfma_f32_16x16x32_bf16(av, b2v, acc[mi][2], 0, 0, 0); \
    acc[mi][3] = __builtin_amdgcn_mfma_f32_16x16x32_bf16(av, b3v, acc[mi][3], 0, 0, 0);

// ---- GEMM keysb·Ua^T + fused tanh + Va dot -> deterministic score slices ----
// 256x256 tile, BK=32, 8 waves (2M x 4N), 4-slot LDS ring (128 KiB).
// Software-pipelined fragments: ds_reads for phase p+1 issued BEFORE phase p's
// MFMA cluster; counted lgkmcnt overlaps DS pipe (~1100 cyc/tile) under MFMA
// pipe (~1240 cyc/tile). ONE barrier per K-tile. vmcnt(4) gate: tiles t and
// t+1 resident at tile-t start (P1 pre-reads slot t+1; vmcnt retires in
// issue order). b-frags ping-pong (next-tile b issued before P1 MFMA uses b).
__global__ __launch_bounds__(512, 2) void gemm_score_kernel(const u16* __restrict__ keysb,
                                                            const u16* __restrict__ uab,
                                                            const float* __restrict__ qb,
                                                            const float* __restrict__ vaw,
                                                            float* __restrict__ sp) {
    __shared__ __align__(16) u16 As[4][BM * BK];   // 4 x 16 KB
    __shared__ __align__(16) u16 Bs[4][BN * BK];   // 4 x 16 KB

    const int tid  = threadIdx.x;
    const int lane = tid & 63;
    const int w    = tid >> 6;          // 0..7
    const int wm   = w >> 2;            // 0..1  -> rows [wm*128, +128)
    const int wn   = w & 3;             // 0..3  -> cols [wn*64, +64)

    // XCD-chunked swizzle: 128 consecutive remapped blocks per XCD, n-fastest
    const int bid = blockIdx.y * 4 + blockIdx.x;         // dispatch order
    const int swz = (bid & 7) * 128 + (bid >> 3);        // bijective (1024 % 8 == 0)
    const int bx  = swz & 3;
    const int by  = swz >> 2;
    const int n0  = bx * BN;
    const int m0  = by * BM;

    // ---- staging addressing (linear LDS dest, pre-swizzled global source) ----
    // row = 64 B = 4 x 16B slots; LDS(r, s) holds global slot s ^ ((r>>1)&3)
    const int srow = lane >> 2;                          // row within 16-row chunk
    const int cs   = (lane & 3) ^ ((lane >> 3) & 3);     // swizzled source slot
    const u16* gA0 = keysb + (size_t)(m0 + w * 32 + srow) * HDIM + cs * 8;
    const u16* gB0 = uab   + (size_t)(n0 + w * 32 + srow) * HDIM + cs * 8;
    const int ldst = w * 32 * BK;                        // wave's 32-row group

    // ---- fragment read addressing (swizzled), as LDS byte offsets ----
    const int fr = lane & 15;
    const int fq = lane >> 4;
    const int sA = fq ^ ((fr >> 1) & 3);                 // row-bit-independent
    const unsigned aB0 = (unsigned)(unsigned long long)(const AS3 u16*)&As[0][0]
                       + (unsigned)(((wm * 128 + fr) * BK + sA * 8) * 2);
    const unsigned bB0 = (unsigned)(unsigned long long)(const AS3 u16*)&Bs[0][0]
                       + (unsigned)(((wn * 64  + fr) * BK + sA * 8) * 2);

    f32x4 acc[8][4] = {};

#define STAGE_A(kt) { \
    u16* d = &As[(kt) & 3][ldst]; \
    __builtin_amdgcn_global_load_lds((AS1 void*)(gA0 + (size_t)(kt) * BK), (AS3 void*)d, 16, 0, 0); \
    __builtin_amdgcn_global_load_lds((AS1 void*)(gA0 + (size_t)(kt) * BK + 16 * HDIM), (AS3 void*)(d + 16 * BK), 16, 0, 0); }
#define STAGE_B(kt) { \
    u16* d = &Bs[(kt) & 3][ldst]; \
    __builtin_amdgcn_global_load_lds((AS1 void*)(gB0 + (size_t)(kt) * BK), (AS3 void*)d, 16, 0, 0); \
    __builtin_amdgcn_global_load_lds((AS1 void*)(gB0 + (size_t)(kt) * BK + 16 * HDIM), (AS3 void*)(d + 16 * BK), 16, 0, 0); }

    bf16x8 a0, a1, a2, a3, a4, a5, a6, a7;
    bf16x8 bA0, bA1, bA2, bA3, bB0v, bB1v, bB2v, bB3v;

    // prologue: tiles 0,1,2 in flight (12 loads/wave); need {0,1} resident
    STAGE_A(0) STAGE_B(0)
    STAGE_A(1) STAGE_B(1)
    STAGE_A(2) STAGE_B(2)
    asm volatile("s_waitcnt vmcnt(4)" ::: "memory");
    __builtin_amdgcn_s_barrier();
    // reads(0, P0)
    DSREAD(a0, aB0, 0);    DSREAD(a1, aB0, 1024);
    DSREAD(a2, aB0, 2048); DSREAD(a3, aB0, 3072);
    DSREAD(bA0, bB0, 0);    DSREAD(bA1, bB0, 1024);
    DSREAD(bA2, bB0, 2048); DSREAD(bA3, bB0, 3072);

#define TILE(t, bc0, bc1, bc2, bc3, bn0, bn1, bn2, bn3) { \
    const unsigned at = aB0 + (((t) & 3) << 14);             /* slot stride 16 KiB */ \
    /* ---- P0: stage A(t+3), prefetch a4-7(t), MFMA mi0-3 ---- */ \
    if ((t) + 3 < KSTEPS) STAGE_A((t) + 3) \
    DSREAD(a4, at, 4096); DSREAD(a5, at, 5120); \
    DSREAD(a6, at, 6144); DSREAD(a7, at, 7168); \
    asm volatile("s_waitcnt lgkmcnt(4)" ::: "memory");       /* reads(t,P0) done */ \
    __builtin_amdgcn_sched_barrier(0); \
    __builtin_amdgcn_s_setprio(1); \
    MFMA4(0, a0, bc0, bc1, bc2, bc3) \
    MFMA4(1, a1, bc0, bc1, bc2, bc3) \
    MFMA4(2, a2, bc0, bc1, bc2, bc3) \
    MFMA4(3, a3, bc0, bc1, bc2, bc3) \
    __builtin_amdgcn_s_setprio(0); \
    /* ---- P1: stage B(t+3), prefetch tile t+1 P0, MFMA mi4-7 ---- */ \
    if ((t) + 3 < KSTEPS) STAGE_B((t) + 3) \
    if ((t) + 1 < KSTEPS) { \
        const unsigned an = aB0 + ((((t) + 1) & 3) << 14); \
        const unsigned bn = bB0 + ((((t) + 1) & 3) << 14); \
        DSREAD(a0, an, 0);    DSREAD(a1, an, 1024); \
        DSREAD(a2, an, 2048); DSREAD(a3, an, 3072); \
        DSREAD(bn0, bn, 0);    DSREAD(bn1, bn, 1024); \
        DSREAD(bn2, bn, 2048); DSREAD(bn3, bn, 3072); \
        asm volatile("s_waitcnt lgkmcnt(8)" ::: "memory");   /* reads(t,P1) done */ \
    } else { \
        asm volatile("s_waitcnt lgkmcnt(0)" ::: "memory"); \
    } \
    __builtin_amdgcn_sched_barrier(0); \
    __builtin_amdgcn_s_setprio(1); \
    MFMA4(4, a4, bc0, bc1, bc2, bc3) \
    MFMA4(5, a5, bc0, bc1, bc2, bc3) \
    MFMA4(6, a6, bc0, bc1, bc2, bc3) \
    MFMA4(7, a7, bc0, bc1, bc2, bc3) \
    __builtin_amdgcn_s_setprio(0); \
    /* ---- boundary: entering t+1 needs {t+1, t+2} resident ---- */ \
    if ((t) + 1 < KSTEPS - 2) asm volatile("s_waitcnt vmcnt(4)" ::: "memory"); \
    else                      asm volatile("s_waitcnt vmcnt(0)" ::: "memory"); \
    __builtin_amdgcn_s_barrier(); \
}

    for (int t = 0; t < KSTEPS; t += 2) {
        TILE(t,     bA0, bA1, bA2, bA3, bB0v, bB1v, bB2v, bB3v)
        TILE(t + 1, bB0v, bB1v, bB2v, bB3v, bA0, bA1, bA2, bA3)
    }
#undef TILE
#undef STAGE_A
#undef STAGE_B

    // epilogue: h = tanh(acc + qb), partial score over this wave's 64 n-cols
    const int bidx = m0 >> 11;   // BM=256 divides SEQ=2048
    float qv[4], vv[4];
    #pragma unroll
    for (int ni = 0; ni < 4; ni++) {
        int n_g = n0 + wn * 64 + ni * 16 + fr;
        qv[ni] = qb[bidx * HDIM + n_g];
        vv[ni] = vaw[n_g];
    }
    const int slice = bx * 4 + wn;
    float* sl = sp + ((size_t)slice * BATCH + bidx) * SEQ;
    #pragma unroll
    for (int mi = 0; mi < 8; mi++) {
        #pragma unroll
        for (int r = 0; r < 4; r++) {
            float p = 0.f;
            #pragma unroll
            for (int ni = 0; ni < 4; ni++) {
                float x = acc[mi][ni][r] + qv[ni];
                float e = __expf(2.f * x);          // tanh = 1 - 2/(e^{2x}+1), NaN-free
                p += (1.f - 2.f / (e + 1.f)) * vv[ni];
            }
            p += __shfl_xor(p, 1);
            p += __shfl_xor(p, 2);
            p += __shfl_xor(p, 4);
            p += __shfl_xor(p, 8);
            if (fr == 0) {
                int s_g = (m0 + wm * 128 + mi * 16 + fq * 4 + r) & (SEQ - 1);
                sl[s_g] = p;
            }
        }
    }
}

// ---- softmax over SEQ per batch; sums 16 slices; zeroes ctx region ----
__global__ __launch_bounds__(256) void softmax_kernel(const float* __restrict__ sp,
                                                      float* __restrict__ weights,
                                                      float* __restrict__ ctx) {
    __shared__ float red[4];
    const int b = blockIdx.x;
    const int tid = threadIdx.x;
    float4 z = {0.f, 0.f, 0.f, 0.f};
    ((float4*)(ctx + b * HDIM))[tid] = z;       // zero context for atomics
    float v[8];
    float mx = -1e30f;
    #pragma unroll
    for (int i = 0; i < 8; i++) {
        int s = tid + i * 256;
        float a = 0.f;
        #pragma unroll
        for (int j = 0; j < NSLICE; j++) a += sp[((size_t)j * BATCH + b) * SEQ + s];
        v[i] = a;
        mx = fmaxf(mx, a);
    }
    #pragma unroll
    for (int m = 1; m < 64; m <<= 1) mx = fmaxf(mx, __shfl_xor(mx, m));
    if ((tid & 63) == 0) red[tid >> 6] = mx;
    __syncthreads();
    mx = fmaxf(fmaxf(red[0], red[1]), fmaxf(red[2], red[3]));
    float sum = 0.f;
    #pragma unroll
    for (int i = 0; i < 8; i++) { v[i] = __expf(v[i] - mx); sum += v[i]; }
    #pragma unroll
    for (int m = 1; m < 64; m <<= 1) sum += __shfl_xor(sum, m);
    __syncthreads();
    if ((tid & 63) == 0) red[tid >> 6] = sum;
    __syncthreads();
    sum = red[0] + red[1] + red[2] + red[3];
    float inv = 1.f / sum;
    #pragma unroll
    for (int i = 0; i < 8; i++) weights[b * SEQ + tid + i * 256] = v[i] * inv;
}

// ---- context[b][h] = sum_s w[b][s] * keysb[b][s][h] (bf16 keys) ----
__global__ __launch_bounds__(256) void context_kernel(const u16* __restrict__ keysb,
                                                      const float* __restrict__ weights,
                                                      float* __restrict__ ctx) {
    __shared__ float wsm[256];
    const int b = blockIdx.x;
    const int s0 = blockIdx.y * 256;
    const int tid = threadIdx.x;
    wsm[tid] = weights[b * SEQ + s0 + tid];
    __syncthreads();
    const int hq = tid & 127;
    const int sh = (tid >> 7) * 128;
    float a0 = 0.f, a1 = 0.f, a2 = 0.f, a3 = 0.f;
    float a4 = 0.f, a5 = 0.f, a6 = 0.f, a7 = 0.f;
    const uint4* kp = (const uint4*)(keysb + (size_t)b * SEQ * HDIM
                                     + (size_t)(s0 + sh) * HDIM) + hq;
    #pragma unroll 8
    for (int s = 0; s < 128; s++) {
        uint4 kv = kp[s * 128];            // row stride = 1024 u16 = 128 uint4
        float wv = wsm[sh + s];
        a0 += wv * __uint_as_float(kv.x << 16);
        a1 += wv * __uint_as_float(kv.x & 0xFFFF0000u);
        a2 += wv * __uint_as_float(kv.y << 16);
        a3 += wv * __uint_as_float(kv.y & 0xFFFF0000u);
        a4 += wv * __uint_as_float(kv.z << 16);
        a5 += wv * __uint_as_float(kv.z & 0xFFFF0000u);
        a6 += wv * __uint_as_float(kv.w << 16);
        a7 += wv * __uint_as_float(kv.w & 0xFFFF0000u);
    }
    float* o = ctx + b * HDIM + hq * 8;
    atomicAdd(o + 0, a0);
    atomicAdd(o + 1, a1);
    atomicAdd(o + 2, a2);
    atomicAdd(o + 3, a3);
    atomicAdd(o + 4, a4);
    atomicAdd(o + 5, a5);
    atomicAdd(o + 6, a6);
    atomicAdd(o + 7, a7);
}

extern "C" void kernel_launch(void* const* d_in, const int* in_sizes, int n_in,
                              void* d_out, int out_size, void* d_ws, size_t ws_size,
                              hipStream_t stream) {
    const float* query = (const float*)d_in[0];
    const float* keys  = (const float*)d_in[1];
    const float* Wa_w  = (const float*)d_in[2];
    const float* Wa_b  = (const float*)d_in[3];
    const float* Ua_w  = (const float*)d_in[4];
    const float* Ua_b  = (const float*)d_in[5];
    const float* Va_w  = (const float*)d_in[6];
    // Va_b unused: softmax is shift-invariant.
    float* out = (float*)d_out;   // [0, 32768) context, [32768, 98304) weights

    char* ws = (char*)d_ws;
    u16*  keysb = (u16*)ws;                                     // 134217728 B
    u16*  uab   = (u16*)(ws + 134217728);                       //   2097152 B
    float* qb   = (float*)(ws + 134217728 + 2097152);           //    131072 B
    float* sp   = (float*)(ws + 134217728 + 2097152 + 131072);  //   4194304 B (16 slices)

    cvt_kernel<<<(BATCH * SEQ * HDIM) / 2048, 256, 0, stream>>>(keys, keysb);
    cvt_kernel<<<(HDIM * HDIM) / 2048, 256, 0, stream>>>(Ua_w, uab);
    qb_kernel<<<dim3(BATCH, HDIM / 64), 256, 0, stream>>>(query, Wa_w, Wa_b, Ua_b, qb);
    gemm_score_kernel<<<dim3(HDIM / BN, M_TOTAL / BM), 512, 0, stream>>>(keysb, uab, qb, Va_w, sp);
    softmax_kernel<<<BATCH, 256, 0, stream>>>(sp, out + BATCH * HDIM, out);
    context_kernel<<<dim3(BATCH, 8), 256, 0, stream>>>(keysb, out + BATCH * HDIM, out);
}